// Round 3
// baseline (410.554 us; speedup 1.0000x reference)
//
#include <hip/hip_runtime.h>

#define T_LEN 3000
#define C_CH 8
#define NTHREADS 256
#define NWAVES 4
#define TT 256                  // time-steps (floats per stream) per chunk
#define NCHUNK 12               // ceil(3000/256); last chunk valid=184
#define NSTREAM 17              // 8 re + 8 im + 1 mask

#define AS1 __attribute__((address_space(1)))
#define AS3 __attribute__((address_space(3)))
// wave-wide: stages 64 lanes x 16 B = 1024 B = 256 floats into LDS at
// (uniform base + lane*16). Global src is per-lane (clamped for tail).
#define GLOAD_LDS(G, L) \
    __builtin_amdgcn_global_load_lds((const AS1 void*)(G), (AS3 void*)(L), 16, 0, 0)

#define XPOSE_ROUND(OFF)                                        \
    {                                                           \
        const bool hi = (lane & (OFF)) != 0;                    \
        _Pragma("unroll")                                       \
        for (int i = 0; i < (OFF); ++i) {                       \
            float send = hi ? acc[i] : acc[i + (OFF)];          \
            float recv = __shfl_xor(send, (OFF));               \
            float keep = hi ? acc[i + (OFF)] : acc[i];          \
            acc[i] = keep + recv;                               \
        }                                                       \
    }

// Stage one chunk: wave w stages streams {w, w+4, w+8, w+12}; wave 0 also
// stages the mask stream (16). Streams 0-7 = Xr channels, 8-15 = Xi channels.
__device__ __forceinline__ void stage(const float* __restrict__ Xr,
                                      const float* __restrict__ Xi,
                                      const float* __restrict__ Mk,
                                      float* buf, int slice, int off,
                                      int wave, int lane) {
    int elem = off + lane * 4;
    if (elem > T_LEN - 4) elem = T_LEN - 4;   // tail clamp (dup data, masked later)
    const size_t xbase = (size_t)slice * (C_CH * T_LEN);
#pragma unroll
    for (int k = 0; k < 4; ++k) {
        const int s = wave + 4 * k;           // 0..15
        const float* g = (s < 8)
            ? (Xr + xbase + (size_t)s * T_LEN + elem)
            : (Xi + xbase + (size_t)(s - 8) * T_LEN + elem);
        GLOAD_LDS(g, buf + s * TT);
    }
    if (wave == 0) {
        const float* g = Mk + (size_t)slice * T_LEN + elem;
        GLOAD_LDS(g, buf + 16 * TT);
    }
}

__global__ __launch_bounds__(NTHREADS, 4) void psd_kernel(
        const float* __restrict__ Xr,
        const float* __restrict__ Xi,
        const float* __restrict__ Mk,
        float* __restrict__ out,
        int real_elems, int write_imag) {
    const int slice = blockIdx.x;
    const int tid   = threadIdx.x;
    const int lane  = tid & 63;
    const int wave  = tid >> 6;

    __shared__ float lds[2][NSTREAM * TT];   // 2 x 17 KB double buffer
    __shared__ float red[NWAVES * 64];
    __shared__ float sred[NWAVES];
    __shared__ float fin[128];

    float acc[64];
#pragma unroll
    for (int k = 0; k < 64; ++k) acc[k] = 0.f;
    float s = 0.f;   // raw mask sum (normalization deferred to epilogue)

    // prologue: stage chunk 0
    stage(Xr, Xi, Mk, lds[0], slice, 0, wave, lane);

    for (int ch = 0; ch < NCHUNK; ++ch) {
        const int cur = ch & 1;
        if (ch + 1 < NCHUNK) {
            stage(Xr, Xi, Mk, lds[cur ^ 1], slice, (ch + 1) * TT, wave, lane);
            // counted vmcnt: keep next chunk's loads in flight, drain current's.
            if (wave == 0) asm volatile("s_waitcnt vmcnt(5)" ::: "memory");
            else           asm volatile("s_waitcnt vmcnt(4)" ::: "memory");
        } else {
            asm volatile("s_waitcnt vmcnt(0)" ::: "memory");
        }
        __builtin_amdgcn_s_barrier();        // raw: does NOT drain vmcnt

        const int rem   = T_LEN - ch * TT;
        const int valid = rem < TT ? rem : TT;
        const float* buf = lds[cur];
        if (tid < valid) {
            const float m = buf[16 * TT + tid];
            s += m;
            float xr[C_CH], xi[C_CH];
#pragma unroll
            for (int c = 0; c < C_CH; ++c) {
                xr[c] = buf[c * TT + tid];
                xi[c] = buf[(8 + c) * TT + tid];
            }
            float mr[C_CH], mi[C_CH];
#pragma unroll
            for (int c = 0; c < C_CH; ++c) {
                mr[c] = m * xr[c];
                mi[c] = m * xi[c];
            }
            // diagonal: re = m*(xr^2 + xi^2)
#pragma unroll
            for (int c = 0; c < C_CH; ++c)
                acc[c] += mr[c] * xr[c] + mi[c] * xi[c];
            // upper triangle: psd[c][e] = sum m * X[c] * conj(X[e])
#pragma unroll
            for (int c = 0; c < C_CH; ++c) {
#pragma unroll
                for (int e = c + 1; e < C_CH; ++e) {
                    const int p = 7 * c - (c * (c - 1)) / 2 + (e - c - 1);
                    acc[8 + p]  += mr[c] * xr[e] + mi[c] * xi[e];
                    acc[36 + p] += mi[c] * xr[e] - mr[c] * xi[e];
                }
            }
        }
        asm volatile("" ::: "memory");
        __builtin_amdgcn_s_barrier();        // protect buf from next stage overwrite
    }

    // ---- per-wave mask-sum reduce (butterfly) ----
#pragma unroll
    for (int off = 32; off > 0; off >>= 1) s += __shfl_xor(s, off);

    // ---- per-wave transpose-reduce: lane k ends with wave-partial of acc k ----
    XPOSE_ROUND(32)
    XPOSE_ROUND(16)
    XPOSE_ROUND(8)
    XPOSE_ROUND(4)
    XPOSE_ROUND(2)
    XPOSE_ROUND(1)
    // acc[0] now = sum over this wave's lanes of accumulator index 'lane'

    // ---- cross-wave combine in (tiny) LDS ----
    red[wave * 64 + lane] = acc[0];
    if (lane == 0) sred[wave] = s;
    __syncthreads();   // vmcnt already 0 here; full sync fine

    if (tid < 64) {
        float tot = (red[tid] + red[64 + tid]) + (red[128 + tid] + red[192 + tid]);
        const float stot = (sred[0] + sred[1]) + (sred[2] + sred[3]);
        tot *= 1.0f / (stot + 1e-15f);

        // scatter into per-slice real/imag planes via Hermitian symmetry
        if (tid < 8) {
            const int c = tid;
            fin[c * 8 + c]      = tot;   // diag re
            fin[64 + c * 8 + c] = 0.f;   // diag im = 0 exactly
        } else {
            int p = (tid < 36) ? (tid - 8) : (tid - 36);
            int c = 0;
            while (p >= 7 - c) { p -= 7 - c; ++c; }
            const int e = c + 1 + p;
            if (tid < 36) {        // real part, symmetric
                fin[c * 8 + e] = tot;
                fin[e * 8 + c] = tot;
            } else {               // imag part, antisymmetric
                fin[64 + c * 8 + e] = tot;
                fin[64 + e * 8 + c] = -tot;
            }
        }
    }
    __syncthreads();
    if (tid < 64) {
        out[(size_t)slice * 64 + tid] = fin[tid];
    } else if (tid < 128 && write_imag) {
        out[(size_t)real_elems + (size_t)slice * 64 + (tid - 64)] = fin[tid];
    }
}

extern "C" void kernel_launch(void* const* d_in, const int* in_sizes, int n_in,
                              void* d_out, int out_size, void* d_ws, size_t ws_size,
                              hipStream_t stream) {
    const float* Xr = (const float*)d_in[0];
    const float* Xi = (const float*)d_in[1];
    const float* Mk = (const float*)d_in[2];
    float* out = (float*)d_out;
    const int slices = in_sizes[2] / T_LEN;   // B*F = 2056
    const int real_elems = slices * 64;       // B*F*C*C = 131584
    const int write_imag = (out_size >= 2 * real_elems) ? 1 : 0;
    psd_kernel<<<dim3(slices), dim3(NTHREADS), 0, stream>>>(Xr, Xi, Mk, out,
                                                            real_elems, write_imag);
}